// Round 2
// baseline (1401.958 us; speedup 1.0000x reference)
//
#include <hip/hip_runtime.h>

#define B_SZ 16384
#define DIM  1024
#define NH   16
#define HD   64
#define FFN_ 4096

typedef __bf16 bf16x8 __attribute__((ext_vector_type(8)));
typedef unsigned short u16x8 __attribute__((ext_vector_type(8)));
typedef float f32x4 __attribute__((ext_vector_type(4)));

__device__ __forceinline__ unsigned short f2bf(float x) {
    union { float f; unsigned int u; } v; v.f = x;
    unsigned int r = v.u + 0x7FFFu + ((v.u >> 16) & 1u);
    return (unsigned short)(r >> 16);
}
__device__ __forceinline__ float bf2f(unsigned short u) {
    union { unsigned int u32; float f; } v; v.u32 = ((unsigned int)u) << 16;
    return v.f;
}

__device__ __forceinline__ void gload16(const void* g, void* lds) {
    __builtin_amdgcn_global_load_lds(
        (__attribute__((address_space(1))) void*)g,
        (__attribute__((address_space(3))) void*)lds,
        16, 0, 0);
}

// ---------------------------------------------------------------------------
// transpose + fp32->bf16 convert: W [K,N] fp32 -> WT [N,K] bf16
// ---------------------------------------------------------------------------
__global__ __launch_bounds__(256) void transpose_conv(
    const float* __restrict__ W, unsigned short* __restrict__ WT, int K, int N)
{
    __shared__ float tile[32][33];
    const int n0 = blockIdx.x * 32, k0 = blockIdx.y * 32;
    const int tx = threadIdx.x, ty = threadIdx.y;
    #pragma unroll
    for (int i = ty; i < 32; i += 8)
        tile[i][tx] = W[(size_t)(k0 + i) * N + n0 + tx];
    __syncthreads();
    #pragma unroll
    for (int i = ty; i < 32; i += 8)
        WT[(size_t)(n0 + i) * K + k0 + tx] = f2bf(tile[tx][i]);
}

// ---------------------------------------------------------------------------
// chunk inputs -> bf16 mods [3,Bc,DIM] and savg = mean(m0,m1,m2) bf16 [Bc,DIM]
// ---------------------------------------------------------------------------
__global__ __launch_bounds__(256) void conv_inputs(
    const float4* __restrict__ m0, const float4* __restrict__ m1,
    const float4* __restrict__ m2,
    ushort4* __restrict__ mods, ushort4* __restrict__ savg, int n4)
{
    int idx = blockIdx.x * blockDim.x + threadIdx.x;
    int stride = gridDim.x * blockDim.x;
    for (int i = idx; i < n4; i += stride) {
        float4 a = m0[i], b = m1[i], c = m2[i];
        ushort4 ua; ua.x = f2bf(a.x); ua.y = f2bf(a.y); ua.z = f2bf(a.z); ua.w = f2bf(a.w);
        ushort4 ub; ub.x = f2bf(b.x); ub.y = f2bf(b.y); ub.z = f2bf(b.z); ub.w = f2bf(b.w);
        ushort4 uc; uc.x = f2bf(c.x); uc.y = f2bf(c.y); uc.z = f2bf(c.z); uc.w = f2bf(c.w);
        mods[i] = ua; mods[n4 + i] = ub; mods[2 * n4 + i] = uc;
        const float k = 1.f / 3.f;
        ushort4 us;
        us.x = f2bf((a.x + b.x + c.x) * k); us.y = f2bf((a.y + b.y + c.y) * k);
        us.z = f2bf((a.z + b.z + c.z) * k); us.w = f2bf((a.w + b.w + c.w) * k);
        savg[i] = us;
    }
}

// ---------------------------------------------------------------------------
// GEMM: C[M,N] = A[M,K] @ BT[N,K]^T (+bias, +epilogue)
// 128x128 tile, BK=32, 256 threads (4 waves, each 64x64 as 4x4 mfma 16x16x32)
// MODE 0: bf16 out = acc+bias
// MODE 1: bf16 out = acc+bias+res            (res fp32)
// MODE 2: bf16 out = relu(acc+bias)
// MODE 3: fp32 out = acc+bias+res
// ---------------------------------------------------------------------------
template <int MODE>
__global__ __launch_bounds__(256) void gemm_bt(
    const unsigned short* __restrict__ A,  // [M,K] bf16
    const unsigned short* __restrict__ BT, // [N,K] bf16
    const float* __restrict__ bias,        // [N]
    const float* __restrict__ res,         // [M,N] fp32 (MODE 1/3)
    unsigned short* __restrict__ outb,     // bf16 out (MODE 0/1/2)
    float* __restrict__ outf,              // fp32 out (MODE 3)
    int K, int N)
{
    __shared__ __align__(16) unsigned short As[128 * 32];
    __shared__ __align__(16) unsigned short Bs[128 * 32];
    const int tid  = threadIdx.x;
    const int lane = tid & 63;
    const int wave = tid >> 6;
    const int wm = (wave >> 1) * 64;
    const int wn = (wave & 1) * 64;
    const int lr = lane & 15;
    const int quad = lane >> 4;

    const size_t rowA = (size_t)blockIdx.y * 128 + (tid >> 2);
    const size_t rowB = (size_t)blockIdx.x * 128 + (tid >> 2);
    const int kcol = (tid & 3) * 8;
    const unsigned short* Ag = A + rowA * K + kcol;
    const unsigned short* Bg = BT + rowB * K + kcol;
    char* aDst = (char*)As + tid * 16;
    char* bDst = (char*)Bs + tid * 16;

    f32x4 zero = {0.f, 0.f, 0.f, 0.f};
    f32x4 acc[4][4];
    #pragma unroll
    for (int i = 0; i < 4; ++i)
        #pragma unroll
        for (int j = 0; j < 4; ++j) acc[i][j] = zero;

    for (int k0 = 0; k0 < K; k0 += 32) {
        gload16(Ag + k0, aDst);
        gload16(Ag + (size_t)64 * K + k0, aDst + 4096);
        gload16(Bg + k0, bDst);
        gload16(Bg + (size_t)64 * K + k0, bDst + 4096);
        __syncthreads();  // drains vmcnt -> LDS tiles ready

        u16x8 af[4], bfr[4];
        #pragma unroll
        for (int mi = 0; mi < 4; ++mi)
            af[mi] = *(const u16x8*)&As[(wm + mi * 16 + lr) * 32 + quad * 8];
        #pragma unroll
        for (int nj = 0; nj < 4; ++nj)
            bfr[nj] = *(const u16x8*)&Bs[(wn + nj * 16 + lr) * 32 + quad * 8];

        #pragma unroll
        for (int mi = 0; mi < 4; ++mi)
            #pragma unroll
            for (int nj = 0; nj < 4; ++nj)
                acc[mi][nj] = __builtin_amdgcn_mfma_f32_16x16x32_bf16(
                    __builtin_bit_cast(bf16x8, af[mi]),
                    __builtin_bit_cast(bf16x8, bfr[nj]),
                    acc[mi][nj], 0, 0, 0);
        __syncthreads();  // protect LDS before next stage
    }

    // epilogue: C/D layout col=lane&15, row=quad*4+reg
    const size_t rbase = (size_t)blockIdx.y * 128 + wm + quad * 4;
    const int cbase = blockIdx.x * 128 + wn + lr;
    #pragma unroll
    for (int mi = 0; mi < 4; ++mi) {
        #pragma unroll
        for (int nj = 0; nj < 4; ++nj) {
            const int gc = cbase + nj * 16;
            const float bv = bias[gc];
            #pragma unroll
            for (int r = 0; r < 4; ++r) {
                const size_t gr = rbase + mi * 16 + r;
                float v = acc[mi][nj][r] + bv;
                if (MODE == 1 || MODE == 3) v += res[gr * N + gc];
                if (MODE == 2) v = v > 0.f ? v : 0.f;
                if (MODE == 3) outf[gr * N + gc] = v;
                else outb[gr * N + gc] = f2bf(v);
            }
        }
    }
}

// ---------------------------------------------------------------------------
// attention (3 keys) + residual + LN1.  One row per block, 256 threads.
// Kb/Vb are [3, Bc, DIM]; jstride = Bc*DIM.
// ---------------------------------------------------------------------------
__global__ __launch_bounds__(256) void attn_ln1(
    const unsigned short* __restrict__ qb,  // [Bc,DIM] bf16
    const unsigned short* __restrict__ Kb,  // [3,Bc,DIM] bf16
    const unsigned short* __restrict__ Vb,  // [3,Bc,DIM] bf16
    const float* __restrict__ domain,
    const float* __restrict__ g1, const float* __restrict__ beta1,
    unsigned short* __restrict__ x1b, float* __restrict__ x1f,
    size_t jstride)
{
    const int b = blockIdx.x;
    const int t = threadIdx.x;
    const int d0 = t * 4;                 // head = t/16 (16 thr x 4 elem = HD 64)
    const size_t base = (size_t)b * DIM + d0;

    float q[4];
    { ushort4 u = *(const ushort4*)(qb + base);
      q[0] = bf2f(u.x); q[1] = bf2f(u.y); q[2] = bf2f(u.z); q[3] = bf2f(u.w); }

    float vv[3][4], s[3];
    #pragma unroll
    for (int j = 0; j < 3; ++j) {
        const size_t off = (size_t)j * jstride + base;
        ushort4 ku = *(const ushort4*)(Kb + off);
        ushort4 vu = *(const ushort4*)(Vb + off);
        float p = q[0] * bf2f(ku.x) + q[1] * bf2f(ku.y) +
                  q[2] * bf2f(ku.z) + q[3] * bf2f(ku.w);
        vv[j][0] = bf2f(vu.x); vv[j][1] = bf2f(vu.y);
        vv[j][2] = bf2f(vu.z); vv[j][3] = bf2f(vu.w);
        p += __shfl_down(p, 8, 16);
        p += __shfl_down(p, 4, 16);
        p += __shfl_down(p, 2, 16);
        p += __shfl_down(p, 1, 16);
        p = __shfl(p, 0, 16);
        s[j] = p * 0.125f;                // 1/sqrt(64)
    }
    float mx = fmaxf(s[0], fmaxf(s[1], s[2]));
    float e0 = __expf(s[0] - mx), e1 = __expf(s[1] - mx), e2 = __expf(s[2] - mx);
    float inv = 1.f / (e0 + e1 + e2);
    float a0 = e0 * inv, a1 = e1 * inv, a2 = e2 * inv;

    float4 dm = *(const float4*)(domain + base);
    float y[4];
    y[0] = dm.x + a0 * vv[0][0] + a1 * vv[1][0] + a2 * vv[2][0];
    y[1] = dm.y + a0 * vv[0][1] + a1 * vv[1][1] + a2 * vv[2][1];
    y[2] = dm.z + a0 * vv[0][2] + a1 * vv[1][2] + a2 * vv[2][2];
    y[3] = dm.w + a0 * vv[0][3] + a1 * vv[1][3] + a2 * vv[2][3];

    float sum = y[0] + y[1] + y[2] + y[3];
    float sq  = y[0]*y[0] + y[1]*y[1] + y[2]*y[2] + y[3]*y[3];
    #pragma unroll
    for (int off = 32; off > 0; off >>= 1) {
        sum += __shfl_down(sum, off, 64);
        sq  += __shfl_down(sq,  off, 64);
    }
    __shared__ float red[8];
    const int wv = t >> 6, ln = t & 63;
    if (ln == 0) { red[wv] = sum; red[4 + wv] = sq; }
    __syncthreads();
    float tot = red[0] + red[1] + red[2] + red[3];
    float tsq = red[4] + red[5] + red[6] + red[7];
    float mu = tot * (1.f / DIM);
    float var = tsq * (1.f / DIM) - mu * mu;
    float rs = rsqrtf(var + 1e-5f);
    #pragma unroll
    for (int i = 0; i < 4; ++i) {
        int d = d0 + i;
        float xv = (y[i] - mu) * rs * g1[d] + beta1[d];
        x1b[base + i] = f2bf(xv);
        x1f[base + i] = xv;
    }
}

// ---------------------------------------------------------------------------
// LN2 + [DIM,3] projection + softmax.  One row per block, 256 threads.
// ---------------------------------------------------------------------------
__global__ __launch_bounds__(256) void ln2_proj(
    const float* __restrict__ xr,          // [Bc,DIM] = x1 + ffn (fp32)
    const float* __restrict__ g2, const float* __restrict__ beta2,
    const float* __restrict__ Ww,          // [DIM,3] fp32
    const float* __restrict__ bw,          // [3]
    float* __restrict__ out)               // [Bc,3] fp32
{
    const int b = blockIdx.x;
    const int t = threadIdx.x;
    const int d0 = t * 4;
    const size_t base = (size_t)b * DIM + d0;
    float4 x = *(const float4*)(xr + base);
    float xs[4] = {x.x, x.y, x.z, x.w};

    float sum = xs[0] + xs[1] + xs[2] + xs[3];
    float sq  = xs[0]*xs[0] + xs[1]*xs[1] + xs[2]*xs[2] + xs[3]*xs[3];
    #pragma unroll
    for (int off = 32; off > 0; off >>= 1) {
        sum += __shfl_down(sum, off, 64);
        sq  += __shfl_down(sq,  off, 64);
    }
    __shared__ float red[8];
    const int wv = t >> 6, ln = t & 63;
    if (ln == 0) { red[wv] = sum; red[4 + wv] = sq; }
    __syncthreads();
    float tot = red[0] + red[1] + red[2] + red[3];
    float tsq = red[4] + red[5] + red[6] + red[7];
    float mu = tot * (1.f / DIM);
    float var = tsq * (1.f / DIM) - mu * mu;
    float rs = rsqrtf(var + 1e-5f);

    float p0 = 0.f, p1 = 0.f, p2 = 0.f;
    #pragma unroll
    for (int i = 0; i < 4; ++i) {
        int d = d0 + i;
        float xv = (xs[i] - mu) * rs * g2[d] + beta2[d];
        p0 += xv * Ww[d * 3 + 0];
        p1 += xv * Ww[d * 3 + 1];
        p2 += xv * Ww[d * 3 + 2];
    }
    #pragma unroll
    for (int off = 32; off > 0; off >>= 1) {
        p0 += __shfl_down(p0, off, 64);
        p1 += __shfl_down(p1, off, 64);
        p2 += __shfl_down(p2, off, 64);
    }
    __shared__ float pr[12];
    if (ln == 0) { pr[wv] = p0; pr[4 + wv] = p1; pr[8 + wv] = p2; }
    __syncthreads();
    if (t == 0) {
        float l0 = pr[0] + pr[1] + pr[2] + pr[3] + bw[0];
        float l1 = pr[4] + pr[5] + pr[6] + pr[7] + bw[1];
        float l2 = pr[8] + pr[9] + pr[10] + pr[11] + bw[2];
        float m = fmaxf(l0, fmaxf(l1, l2));
        float e0 = __expf(l0 - m), e1 = __expf(l1 - m), e2 = __expf(l2 - m);
        float inv = 1.f / (e0 + e1 + e2);
        out[(size_t)b * 3 + 0] = e0 * inv;
        out[(size_t)b * 3 + 1] = e1 * inv;
        out[(size_t)b * 3 + 2] = e2 * inv;
    }
}

// ---------------------------------------------------------------------------
extern "C" void kernel_launch(void* const* d_in, const int* in_sizes, int n_in,
                              void* d_out, int out_size, void* d_ws, size_t ws_size,
                              hipStream_t stream)
{
    const float* m0     = (const float*)d_in[0];
    const float* m1     = (const float*)d_in[1];
    const float* m2     = (const float*)d_in[2];
    const float* domain = (const float*)d_in[3];
    const float* Wg = (const float*)d_in[4];  const float* bg = (const float*)d_in[5];
    const float* Wq = (const float*)d_in[6];  const float* bq = (const float*)d_in[7];
    const float* Wk = (const float*)d_in[8];  const float* bk = (const float*)d_in[9];
    const float* Wv = (const float*)d_in[10]; const float* bv = (const float*)d_in[11];
    const float* W1 = (const float*)d_in[12]; const float* b1 = (const float*)d_in[13];
    const float* W2 = (const float*)d_in[14]; const float* b2 = (const float*)d_in[15];
    const float* g1 = (const float*)d_in[16]; const float* beta1 = (const float*)d_in[17];
    const float* g2 = (const float*)d_in[18]; const float* beta2 = (const float*)d_in[19];
    const float* Ww = (const float*)d_in[20]; const float* bw = (const float*)d_in[21];
    float* out = (float*)d_out;

    char* ws = (char*)d_ws;
    constexpr size_t SZ_DD_BF = (size_t)DIM * DIM * 2;   // 2 MiB
    constexpr size_t SZ_DF_BF = (size_t)DIM * FFN_ * 2;  // 8 MiB
    constexpr size_t SZ_W = 4 * SZ_DD_BF + 2 * SZ_DF_BF; // 24 MiB

    // --- choose chunking so 24 MiB (weights) + 15 units fit in ws_size ---
    // unit = Bc*DIM*2 bytes; buffers (in units): mods 3, savg 1, dq 1, qb 1,
    // Kb 3, Vb 3, x1b 1, x1f 2.  h1 (4u) overlays mods+savg; xr (2u) overlays Kb.
    int NCH = 16;
    for (int c = 1; c <= 16; c <<= 1) {
        size_t unit = (size_t)(B_SZ / c) * DIM * 2;
        if (SZ_W + 15 * unit <= ws_size) { NCH = c; break; }
    }
    const int Bc = B_SZ / NCH;
    const size_t unit = (size_t)Bc * DIM * 2;

    unsigned short* wgT = (unsigned short*)(ws);
    unsigned short* wqT = (unsigned short*)(ws + SZ_DD_BF);
    unsigned short* wkT = (unsigned short*)(ws + 2 * SZ_DD_BF);
    unsigned short* wvT = (unsigned short*)(ws + 3 * SZ_DD_BF);
    unsigned short* w1T = (unsigned short*)(ws + 4 * SZ_DD_BF);
    unsigned short* w2T = (unsigned short*)(ws + 4 * SZ_DD_BF + SZ_DF_BF);

    char* cb = ws + SZ_W;
    unsigned short* mods = (unsigned short*)(cb);             // 3u
    unsigned short* savg = (unsigned short*)(cb + 3 * unit);  // 1u
    unsigned short* dq   = (unsigned short*)(cb + 4 * unit);  // 1u
    unsigned short* qb   = (unsigned short*)(cb + 5 * unit);  // 1u
    unsigned short* Kb   = (unsigned short*)(cb + 6 * unit);  // 3u
    unsigned short* Vb   = (unsigned short*)(cb + 9 * unit);  // 3u
    unsigned short* x1b  = (unsigned short*)(cb + 12 * unit); // 1u
    float*          x1f  = (float*)(cb + 13 * unit);          // 2u
    unsigned short* h1   = (unsigned short*)(cb);             // 4u over mods+savg
    float*          xr   = (float*)(cb + 6 * unit);           // 2u over Kb

    const dim3 tb(32, 8);
    transpose_conv<<<dim3(DIM / 32, DIM / 32), tb, 0, stream>>>(Wg, wgT, DIM, DIM);
    transpose_conv<<<dim3(DIM / 32, DIM / 32), tb, 0, stream>>>(Wq, wqT, DIM, DIM);
    transpose_conv<<<dim3(DIM / 32, DIM / 32), tb, 0, stream>>>(Wk, wkT, DIM, DIM);
    transpose_conv<<<dim3(DIM / 32, DIM / 32), tb, 0, stream>>>(Wv, wvT, DIM, DIM);
    transpose_conv<<<dim3(FFN_ / 32, DIM / 32), tb, 0, stream>>>(W1, w1T, DIM, FFN_);
    transpose_conv<<<dim3(DIM / 32, FFN_ / 32), tb, 0, stream>>>(W2, w2T, FFN_, DIM);

    for (int c = 0; c < NCH; ++c) {
        const size_t roff = (size_t)c * Bc * DIM;   // element offset into [B,DIM]
        const int n4 = Bc * DIM / 4;
        const int cgrid = (n4 + 255) / 256 < 4096 ? (n4 + 255) / 256 : 4096;

        conv_inputs<<<cgrid, 256, 0, stream>>>(
            (const float4*)(m0 + roff), (const float4*)(m1 + roff),
            (const float4*)(m2 + roff),
            (ushort4*)mods, (ushort4*)savg, n4);

        // 1) dq = bf16(domain + savg@Wg + bg)
        gemm_bt<1><<<dim3(DIM / 128, Bc / 128), 256, 0, stream>>>(
            savg, wgT, bg, domain + roff, dq, nullptr, DIM, DIM);
        // 2) q = dq@Wq + bq
        gemm_bt<0><<<dim3(DIM / 128, Bc / 128), 256, 0, stream>>>(
            dq, wqT, bq, nullptr, qb, nullptr, DIM, DIM);
        // 3) K = mods@Wk + bk   (M = 3*Bc)
        gemm_bt<0><<<dim3(DIM / 128, 3 * Bc / 128), 256, 0, stream>>>(
            mods, wkT, bk, nullptr, Kb, nullptr, DIM, DIM);
        // 4) V = mods@Wv + bv
        gemm_bt<0><<<dim3(DIM / 128, 3 * Bc / 128), 256, 0, stream>>>(
            mods, wvT, bv, nullptr, Vb, nullptr, DIM, DIM);
        // 5) attention + residual + LN1
        attn_ln1<<<Bc, 256, 0, stream>>>(qb, Kb, Vb, domain + roff, g1, beta1,
                                         x1b, x1f, (size_t)Bc * DIM);
        // 6) h1 = relu(x1@W1 + b1)
        gemm_bt<2><<<dim3(FFN_ / 128, Bc / 128), 256, 0, stream>>>(
            x1b, w1T, b1, nullptr, h1, nullptr, DIM, FFN_);
        // 7) xr = x1 + h1@W2 + b2   (fp32)
        gemm_bt<3><<<dim3(DIM / 128, Bc / 128), 256, 0, stream>>>(
            h1, w2T, b2, x1f, nullptr, xr, FFN_, DIM);
        // 8) LN2 + Ww projection + softmax
        ln2_proj<<<Bc, 256, 0, stream>>>(xr, g2, beta2, Ww, bw,
                                         out + (size_t)c * Bc * 3);
    }
}

// Round 3
// 1313.005 us; speedup vs baseline: 1.0677x; 1.0677x over previous
//
#include <hip/hip_runtime.h>

#define B_SZ 16384
#define DIM  1024
#define NH   16
#define HD   64
#define FFN_ 4096

typedef __bf16 bf16x8 __attribute__((ext_vector_type(8)));
typedef unsigned short u16x8 __attribute__((ext_vector_type(8)));
typedef float f32x4 __attribute__((ext_vector_type(4)));

__device__ __forceinline__ unsigned short f2bf(float x) {
    union { float f; unsigned int u; } v; v.f = x;
    unsigned int r = v.u + 0x7FFFu + ((v.u >> 16) & 1u);
    return (unsigned short)(r >> 16);
}
__device__ __forceinline__ float bf2f(unsigned short u) {
    union { unsigned int u32; float f; } v; v.u32 = ((unsigned int)u) << 16;
    return v.f;
}

__device__ __forceinline__ void gload16(const void* g, void* lds) {
    __builtin_amdgcn_global_load_lds(
        (__attribute__((address_space(1))) void*)g,
        (__attribute__((address_space(3))) void*)lds,
        16, 0, 0);
}

// ---------------------------------------------------------------------------
// transpose + fp32->bf16 convert: W [K,N] fp32 -> WT [N,K] bf16
// ---------------------------------------------------------------------------
__global__ __launch_bounds__(256) void transpose_conv(
    const float* __restrict__ W, unsigned short* __restrict__ WT, int K, int N)
{
    __shared__ float tile[32][33];
    const int n0 = blockIdx.x * 32, k0 = blockIdx.y * 32;
    const int tx = threadIdx.x, ty = threadIdx.y;
    #pragma unroll
    for (int i = ty; i < 32; i += 8)
        tile[i][tx] = W[(size_t)(k0 + i) * N + n0 + tx];
    __syncthreads();
    #pragma unroll
    for (int i = ty; i < 32; i += 8)
        WT[(size_t)(n0 + i) * K + k0 + tx] = f2bf(tile[tx][i]);
}

__global__ __launch_bounds__(256) void concat_bias(
    const float* __restrict__ bk, const float* __restrict__ bv,
    float* __restrict__ bkv)
{
    int i = blockIdx.x * 256 + threadIdx.x;
    if (i < 1024) { bkv[i] = bk[i]; bkv[1024 + i] = bv[i]; }
}

// savg = bf16(mean(m0,m1,m2))  full B
__global__ __launch_bounds__(256) void conv_inputs(
    const float4* __restrict__ m0, const float4* __restrict__ m1,
    const float4* __restrict__ m2, ushort4* __restrict__ savg, int n4)
{
    int idx = blockIdx.x * blockDim.x + threadIdx.x;
    int stride = gridDim.x * blockDim.x;
    const float k = 1.f / 3.f;
    for (int i = idx; i < n4; i += stride) {
        float4 a = m0[i], b = m1[i], c = m2[i];
        ushort4 us;
        us.x = f2bf((a.x + b.x + c.x) * k); us.y = f2bf((a.y + b.y + c.y) * k);
        us.z = f2bf((a.z + b.z + c.z) * k); us.w = f2bf((a.w + b.w + c.w) * k);
        savg[i] = us;
    }
}

// ---------------------------------------------------------------------------
// GEMM: C[M,N] = A[M,K] @ BT[N,K]^T (+bias, +epilogue)
// 128x128 tile, BK=64 as two 128x32 sub-tiles per barrier (32 MFMA/barrier).
// blockIdx.x = M-tile (fast-varying -> consecutive blocks share B panel, L2 reuse)
// blockIdx.y = N-tile
// AF32: A is fp32, read from one of {A0,A1,A2} by row-range (KV projection);
//       staged to LDS with XOR-16B-chunk swizzle, trunc-packed to bf16.
// MODE 0: bf16 out = acc+bias
// MODE 1: bf16 out = acc+bias+fp32 res
// MODE 2: bf16 out = relu(acc+bias)
// MODE 4: fp32 out = acc+bias+bf16 res
// ---------------------------------------------------------------------------
template <int MODE, bool AF32>
__global__ __launch_bounds__(256) void gemm2(
    const unsigned short* __restrict__ A,   // [M,K] bf16 (when !AF32)
    const float* __restrict__ A0, const float* __restrict__ A1,
    const float* __restrict__ A2, int chunk0, int Bc,
    const unsigned short* __restrict__ BT,  // [N,K] bf16
    const float* __restrict__ bias,         // [N]
    const void* __restrict__ res,
    void* __restrict__ out, int K, int N)
{
    __shared__ __align__(16) char AsRaw[AF32 ? 32768 : 16384];
    __shared__ __align__(16) unsigned short Bs[2][4096];

    const int tid  = threadIdx.x;
    const int lane = tid & 63;
    const int wave = tid >> 6;
    const int wm = (wave >> 1) * 64;
    const int wn = (wave & 1) * 64;
    const int lr = lane & 15;
    const int quad = lane >> 4;

    // --- B staging addresses (bf16, row stride K) ---
    const size_t rowB = (size_t)blockIdx.y * 128 + (tid >> 2);
    const int kcolB = (tid & 3) * 8;
    const unsigned short* Bg = BT + rowB * K + kcolB;

    // --- A source ---
    const unsigned short* Ag = nullptr;
    const float* Agf = nullptr;
    if constexpr (AF32) {
        const int grow = blockIdx.x * 128;       // in [0, 3*Bc)
        const int j = grow / Bc;
        const int b0 = (grow - j * Bc) + chunk0; // row in [0, B)
        const float* msrc = (j == 0) ? A0 : (j == 1) ? A1 : A2;
        // lane covers (row = tid>>3, chunk = (tid&7) ^ ((tid>>3)&7)) per pass
        const int arow = tid >> 3;
        const int jj = (tid & 7) ^ (arow & 7);
        Agf = msrc + (size_t)(b0 + arow) * DIM + jj * 4;
    } else {
        const size_t rowA = (size_t)blockIdx.x * 128 + (tid >> 2);
        Ag = A + rowA * K + kcolB;
    }

    f32x4 zero = {0.f, 0.f, 0.f, 0.f};
    f32x4 acc[4][4];
    #pragma unroll
    for (int i = 0; i < 4; ++i)
        #pragma unroll
        for (int j = 0; j < 4; ++j) acc[i][j] = zero;

    for (int k0 = 0; k0 < K; k0 += 64) {
        // ---- stage A ----
        if constexpr (AF32) {
            float* Asf = (float*)AsRaw;          // [2][128*32]
            #pragma unroll
            for (int h = 0; h < 2; ++h) {
                #pragma unroll
                for (int i = 0; i < 4; ++i)
                    gload16(Agf + (size_t)i * 32 * DIM + k0 + 32 * h,
                            (char*)(Asf + h * 4096) + i * 4096 + tid * 16);
            }
        } else {
            unsigned short* As = (unsigned short*)AsRaw;  // [2][128*32]
            gload16(Ag + k0,                 (char*)As + tid * 16);
            gload16(Ag + (size_t)64 * K + k0,(char*)As + 4096 + tid * 16);
            gload16(Ag + k0 + 32,            (char*)As + 8192 + tid * 16);
            gload16(Ag + (size_t)64 * K + k0 + 32,
                                             (char*)As + 12288 + tid * 16);
        }
        // ---- stage B ----
        gload16(Bg + k0,                  (char*)Bs[0] + tid * 16);
        gload16(Bg + (size_t)64 * K + k0, (char*)Bs[0] + 4096 + tid * 16);
        gload16(Bg + k0 + 32,             (char*)Bs[1] + tid * 16);
        gload16(Bg + (size_t)64 * K + k0 + 32,
                                          (char*)Bs[1] + 4096 + tid * 16);
        __syncthreads();

        #pragma unroll
        for (int h = 0; h < 2; ++h) {
            u16x8 af[4], bfr[4];
            if constexpr (AF32) {
                const float* Asf = (const float*)AsRaw + h * 4096;
                #pragma unroll
                for (int mi = 0; mi < 4; ++mi) {
                    const int r = wm + mi * 16 + lr;
                    const int s = lr & 7;
                    const float* rp = Asf + r * 32;
                    union { f32x4 f; unsigned int u[4]; } a0, a1;
                    a0.f = *(const f32x4*)(rp + (((quad << 1) ^ s) << 2));
                    a1.f = *(const f32x4*)(rp + ((((quad << 1) | 1) ^ s) << 2));
                    union { unsigned int i[4]; u16x8 v; } pk;
                    pk.i[0] = __builtin_amdgcn_perm(a0.u[1], a0.u[0], 0x07060302);
                    pk.i[1] = __builtin_amdgcn_perm(a0.u[3], a0.u[2], 0x07060302);
                    pk.i[2] = __builtin_amdgcn_perm(a1.u[1], a1.u[0], 0x07060302);
                    pk.i[3] = __builtin_amdgcn_perm(a1.u[3], a1.u[2], 0x07060302);
                    af[mi] = pk.v;
                }
            } else {
                const unsigned short* As =
                    (const unsigned short*)AsRaw + h * 4096;
                #pragma unroll
                for (int mi = 0; mi < 4; ++mi)
                    af[mi] = *(const u16x8*)&As[(wm + mi * 16 + lr) * 32 + quad * 8];
            }
            #pragma unroll
            for (int nj = 0; nj < 4; ++nj)
                bfr[nj] = *(const u16x8*)&Bs[h][(wn + nj * 16 + lr) * 32 + quad * 8];

            #pragma unroll
            for (int mi = 0; mi < 4; ++mi)
                #pragma unroll
                for (int nj = 0; nj < 4; ++nj)
                    acc[mi][nj] = __builtin_amdgcn_mfma_f32_16x16x32_bf16(
                        __builtin_bit_cast(bf16x8, af[mi]),
                        __builtin_bit_cast(bf16x8, bfr[nj]),
                        acc[mi][nj], 0, 0, 0);
        }
        __syncthreads();
    }

    // epilogue: C/D layout col=lane&15, row=quad*4+reg
    const size_t rbase = (size_t)blockIdx.x * 128 + wm + quad * 4;
    const int cbase = blockIdx.y * 128 + wn + lr;
    #pragma unroll
    for (int mi = 0; mi < 4; ++mi) {
        #pragma unroll
        for (int nj = 0; nj < 4; ++nj) {
            const int gc = cbase + nj * 16;
            const float bv = bias[gc];
            #pragma unroll
            for (int r = 0; r < 4; ++r) {
                const size_t gr = rbase + mi * 16 + r;
                float v = acc[mi][nj][r] + bv;
                if (MODE == 1) v += ((const float*)res)[gr * N + gc];
                if (MODE == 2) v = v > 0.f ? v : 0.f;
                if (MODE == 4) {
                    v += bf2f(((const unsigned short*)res)[gr * N + gc]);
                    ((float*)out)[gr * N + gc] = v;
                } else {
                    ((unsigned short*)out)[gr * N + gc] = f2bf(v);
                }
            }
        }
    }
}

// ---------------------------------------------------------------------------
// attention (3 keys) + residual + LN1.  One row per block, 256 threads.
// KVb is [3, Bc, 2048] (cols 0..1023 = K, 1024..2047 = V), chunk-local rows.
// qb / x1b / domain are full-B, indexed at chunk0 + b.
// ---------------------------------------------------------------------------
__global__ __launch_bounds__(256) void attn_ln1(
    const unsigned short* __restrict__ qb,
    const unsigned short* __restrict__ KVb,
    const float* __restrict__ domain,
    const float* __restrict__ g1, const float* __restrict__ beta1,
    unsigned short* __restrict__ x1b, int chunk0, int Bc)
{
    const int b = blockIdx.x;
    const int t = threadIdx.x;
    const int d0 = t * 4;                 // head = t/16
    const size_t gbase = (size_t)(chunk0 + b) * DIM + d0;

    float q[4];
    { ushort4 u = *(const ushort4*)(qb + gbase);
      q[0] = bf2f(u.x); q[1] = bf2f(u.y); q[2] = bf2f(u.z); q[3] = bf2f(u.w); }

    float vv[3][4], s[3];
    #pragma unroll
    for (int j = 0; j < 3; ++j) {
        const size_t off = ((size_t)j * Bc + b) * 2048 + d0;
        ushort4 ku = *(const ushort4*)(KVb + off);
        ushort4 vu = *(const ushort4*)(KVb + off + 1024);
        float p = q[0] * bf2f(ku.x) + q[1] * bf2f(ku.y) +
                  q[2] * bf2f(ku.z) + q[3] * bf2f(ku.w);
        vv[j][0] = bf2f(vu.x); vv[j][1] = bf2f(vu.y);
        vv[j][2] = bf2f(vu.z); vv[j][3] = bf2f(vu.w);
        p += __shfl_down(p, 8, 16);
        p += __shfl_down(p, 4, 16);
        p += __shfl_down(p, 2, 16);
        p += __shfl_down(p, 1, 16);
        p = __shfl(p, 0, 16);
        s[j] = p * 0.125f;                // 1/sqrt(64)
    }
    float mx = fmaxf(s[0], fmaxf(s[1], s[2]));
    float e0 = __expf(s[0] - mx), e1 = __expf(s[1] - mx), e2 = __expf(s[2] - mx);
    float inv = 1.f / (e0 + e1 + e2);
    float a0 = e0 * inv, a1 = e1 * inv, a2 = e2 * inv;

    float4 dm = *(const float4*)(domain + gbase);
    float y[4];
    y[0] = dm.x + a0 * vv[0][0] + a1 * vv[1][0] + a2 * vv[2][0];
    y[1] = dm.y + a0 * vv[0][1] + a1 * vv[1][1] + a2 * vv[2][1];
    y[2] = dm.z + a0 * vv[0][2] + a1 * vv[1][2] + a2 * vv[2][2];
    y[3] = dm.w + a0 * vv[0][3] + a1 * vv[1][3] + a2 * vv[2][3];

    float sum = y[0] + y[1] + y[2] + y[3];
    float sq  = y[0]*y[0] + y[1]*y[1] + y[2]*y[2] + y[3]*y[3];
    #pragma unroll
    for (int off = 32; off > 0; off >>= 1) {
        sum += __shfl_down(sum, off, 64);
        sq  += __shfl_down(sq,  off, 64);
    }
    __shared__ float red[8];
    const int wv = t >> 6, ln = t & 63;
    if (ln == 0) { red[wv] = sum; red[4 + wv] = sq; }
    __syncthreads();
    float tot = red[0] + red[1] + red[2] + red[3];
    float tsq = red[4] + red[5] + red[6] + red[7];
    float mu = tot * (1.f / DIM);
    float var = tsq * (1.f / DIM) - mu * mu;
    float rs = rsqrtf(var + 1e-5f);
    #pragma unroll
    for (int i = 0; i < 4; ++i) {
        int d = d0 + i;
        float xv = (y[i] - mu) * rs * g1[d] + beta1[d];
        x1b[gbase + i] = f2bf(xv);
    }
}

// ---------------------------------------------------------------------------
// LN2 + [DIM,3] projection + softmax.  One row per block, 256 threads.
// xr chunk-local [Bc,DIM] fp32; out written at chunk0 + b.
// ---------------------------------------------------------------------------
__global__ __launch_bounds__(256) void ln2_proj(
    const float* __restrict__ xr,
    const float* __restrict__ g2, const float* __restrict__ beta2,
    const float* __restrict__ Ww, const float* __restrict__ bw,
    float* __restrict__ out, int chunk0)
{
    const int b = blockIdx.x;
    const int t = threadIdx.x;
    const int d0 = t * 4;
    const size_t base = (size_t)b * DIM + d0;
    float4 x = *(const float4*)(xr + base);
    float xs[4] = {x.x, x.y, x.z, x.w};

    float sum = xs[0] + xs[1] + xs[2] + xs[3];
    float sq  = xs[0]*xs[0] + xs[1]*xs[1] + xs[2]*xs[2] + xs[3]*xs[3];
    #pragma unroll
    for (int off = 32; off > 0; off >>= 1) {
        sum += __shfl_down(sum, off, 64);
        sq  += __shfl_down(sq,  off, 64);
    }
    __shared__ float red[8];
    const int wv = t >> 6, ln = t & 63;
    if (ln == 0) { red[wv] = sum; red[4 + wv] = sq; }
    __syncthreads();
    float tot = red[0] + red[1] + red[2] + red[3];
    float tsq = red[4] + red[5] + red[6] + red[7];
    float mu = tot * (1.f / DIM);
    float var = tsq * (1.f / DIM) - mu * mu;
    float rs = rsqrtf(var + 1e-5f);

    float p0 = 0.f, p1 = 0.f, p2 = 0.f;
    #pragma unroll
    for (int i = 0; i < 4; ++i) {
        int d = d0 + i;
        float xv = (xs[i] - mu) * rs * g2[d] + beta2[d];
        p0 += xv * Ww[d * 3 + 0];
        p1 += xv * Ww[d * 3 + 1];
        p2 += xv * Ww[d * 3 + 2];
    }
    #pragma unroll
    for (int off = 32; off > 0; off >>= 1) {
        p0 += __shfl_down(p0, off, 64);
        p1 += __shfl_down(p1, off, 64);
        p2 += __shfl_down(p2, off, 64);
    }
    __shared__ float pr[12];
    if (ln == 0) { pr[wv] = p0; pr[4 + wv] = p1; pr[8 + wv] = p2; }
    __syncthreads();
    if (t == 0) {
        float l0 = pr[0] + pr[1] + pr[2] + pr[3] + bw[0];
        float l1 = pr[4] + pr[5] + pr[6] + pr[7] + bw[1];
        float l2 = pr[8] + pr[9] + pr[10] + pr[11] + bw[2];
        float m = fmaxf(l0, fmaxf(l1, l2));
        float e0 = __expf(l0 - m), e1 = __expf(l1 - m), e2 = __expf(l2 - m);
        float inv = 1.f / (e0 + e1 + e2);
        out[(size_t)(chunk0 + b) * 3 + 0] = e0 * inv;
        out[(size_t)(chunk0 + b) * 3 + 1] = e1 * inv;
        out[(size_t)(chunk0 + b) * 3 + 2] = e2 * inv;
    }
}

// ---------------------------------------------------------------------------
extern "C" void kernel_launch(void* const* d_in, const int* in_sizes, int n_in,
                              void* d_out, int out_size, void* d_ws, size_t ws_size,
                              hipStream_t stream)
{
    const float* m0     = (const float*)d_in[0];
    const float* m1     = (const float*)d_in[1];
    const float* m2     = (const float*)d_in[2];
    const float* domain = (const float*)d_in[3];
    const float* Wg = (const float*)d_in[4];  const float* bg = (const float*)d_in[5];
    const float* Wq = (const float*)d_in[6];  const float* bq = (const float*)d_in[7];
    const float* Wk = (const float*)d_in[8];  const float* bk = (const float*)d_in[9];
    const float* Wv = (const float*)d_in[10]; const float* bv = (const float*)d_in[11];
    const float* W1 = (const float*)d_in[12]; const float* b1 = (const float*)d_in[13];
    const float* W2 = (const float*)d_in[14]; const float* b2 = (const float*)d_in[15];
    const float* g1 = (const float*)d_in[16]; const float* beta1 = (const float*)d_in[17];
    const float* g2 = (const float*)d_in[18]; const float* beta2 = (const float*)d_in[19];
    const float* Ww = (const float*)d_in[20]; const float* bw = (const float*)d_in[21];
    float* out = (float*)d_out;

    char* ws = (char*)d_ws;
    const size_t MiB = 1u << 20;

    // Tier: ws guaranteed >= 150 MiB (round-2 NCH=4 ran). T2 if >= 185 MiB.
    const bool T2 = ws_size >= 185 * MiB;
    const int BcKV = T2 ? 8192 : 4096;   // chunk rows for KV gemm + attention
    const int BcF  = T2 ? 8192 : 4096;   // chunk rows for FFN

    unsigned short* wgT  = (unsigned short*)(ws);
    unsigned short* wqT  = (unsigned short*)(ws + 2 * MiB);
    unsigned short* wkvT = (unsigned short*)(ws + 4 * MiB);   // [2048,1024]
    unsigned short* w1T  = (unsigned short*)(ws + 8 * MiB);
    unsigned short* w2T  = (unsigned short*)(ws + 16 * MiB);
    float*          bkv  = (float*)(ws + 24 * MiB);           // 8 KB

    char* base = ws + 25 * MiB;
    // savg [B,DIM] bf16 (conv -> Wg), then qb overlays it (Wq -> attn)
    unsigned short* savg = (unsigned short*)(base);
    unsigned short* qb   = (unsigned short*)(base);
    unsigned short* x1b  = (unsigned short*)(base + 32 * MiB); // attn -> W2
    unsigned short* dq   = (unsigned short*)(base + 64 * MiB); // Wg -> Wq
    unsigned short* KVb  = (unsigned short*)(base + 64 * MiB); // per-chunk, over dq
    unsigned short* h1   = (unsigned short*)(base + 64 * MiB); // FFN, over KVb
    float*          xr   = (float*)(base + 64 * MiB + (size_t)BcF * FFN_ * 2);

    const dim3 tb(32, 8);
    transpose_conv<<<dim3(DIM / 32, DIM / 32), tb, 0, stream>>>(Wg, wgT, DIM, DIM);
    transpose_conv<<<dim3(DIM / 32, DIM / 32), tb, 0, stream>>>(Wq, wqT, DIM, DIM);
    transpose_conv<<<dim3(DIM / 32, DIM / 32), tb, 0, stream>>>(Wk, wkvT, DIM, DIM);
    transpose_conv<<<dim3(DIM / 32, DIM / 32), tb, 0, stream>>>(
        Wv, wkvT + (size_t)DIM * DIM, DIM, DIM);
    transpose_conv<<<dim3(FFN_ / 32, DIM / 32), tb, 0, stream>>>(W1, w1T, DIM, FFN_);
    transpose_conv<<<dim3(DIM / 32, FFN_ / 32), tb, 0, stream>>>(W2, w2T, FFN_, DIM);
    concat_bias<<<4, 256, 0, stream>>>(bk, bv, bkv);

    conv_inputs<<<8192, 256, 0, stream>>>(
        (const float4*)m0, (const float4*)m1, (const float4*)m2,
        (ushort4*)savg, B_SZ * DIM / 4);

    // 1) dq = bf16(domain + savg@Wg + bg)   full B, grid (128, 8)
    gemm2<1, false><<<dim3(B_SZ / 128, DIM / 128), 256, 0, stream>>>(
        savg, nullptr, nullptr, nullptr, 0, 0, wgT, bg, domain, dq, DIM, DIM);
    // 2) qb = dq@Wq + bq                    full B
    gemm2<0, false><<<dim3(B_SZ / 128, DIM / 128), 256, 0, stream>>>(
        dq, nullptr, nullptr, nullptr, 0, 0, wqT, bq, nullptr, qb, DIM, DIM);

    // 3) per-chunk: KV = [m_j rows]@[Wk|Wv] + bkv ; attention + LN1 -> x1b
    for (int c = 0; c < B_SZ / BcKV; ++c) {
        const int chunk0 = c * BcKV;
        gemm2<0, true><<<dim3(3 * BcKV / 128, 2048 / 128), 256, 0, stream>>>(
            nullptr, m0, m1, m2, chunk0, BcKV, wkvT, bkv, nullptr, KVb,
            DIM, 2048);
        attn_ln1<<<BcKV, 256, 0, stream>>>(qb, KVb, domain, g1, beta1,
                                           x1b, chunk0, BcKV);
    }

    // 4) per-chunk FFN: h1 = relu(x1@W1+b1); xr = x1 + h1@W2 + b2; LN2+proj
    for (int c = 0; c < B_SZ / BcF; ++c) {
        const int chunk0 = c * BcF;
        const unsigned short* x1c = x1b + (size_t)chunk0 * DIM;
        gemm2<2, false><<<dim3(BcF / 128, FFN_ / 128), 256, 0, stream>>>(
            x1c, nullptr, nullptr, nullptr, 0, 0, w1T, b1, nullptr, h1,
            DIM, FFN_);
        gemm2<4, false><<<dim3(BcF / 128, DIM / 128), 256, 0, stream>>>(
            h1, nullptr, nullptr, nullptr, 0, 0, w2T, b2, x1c, xr,
            FFN_, DIM);
        ln2_proj<<<BcF, 256, 0, stream>>>(xr, g2, beta2, Ww, bw, out, chunk0);
    }
}